// Round 11
// baseline (578.233 us; speedup 1.0000x reference)
//
#include <hip/hip_runtime.h>
#include <hip/hip_bf16.h>
#include <math.h>

#define D 1024
#define NP 128
#define BS 2
#define GEO 64
#define TOPKN 18
#define NPAIR (BS*NP*NP)   // 32768

__device__ __forceinline__ float relu_(float x){ return fmaxf(x, 0.f); }
__device__ __forceinline__ unsigned short f2b(float x){
    __hip_bfloat16 h = __float2bfloat16(x);
    return *(unsigned short*)&h;
}
__device__ __forceinline__ float b2f(unsigned short u){
    return __uint_as_float((unsigned)u << 16);
}

typedef short bf16x8 __attribute__((ext_vector_type(8)));
typedef float f32x4  __attribute__((ext_vector_type(4)));

// async global->LDS, 16B per lane. LDS dest must be wave-uniform base + lane*16.
__device__ __forceinline__ void glds16(const unsigned short* g, unsigned short* l){
    __builtin_amdgcn_global_load_lds(
        (const __attribute__((address_space(1))) void*)g,
        (__attribute__((address_space(3))) void*)l,
        16, 0, 0);
}

// ---------------- geo embedding + 3x Linear(64,64) MLP (chunk-local, bf16 out) ----
__global__ __launch_bounds__(256) void k_geo(
    const float* __restrict__ prop,
    const float* __restrict__ gw1, const float* __restrict__ gb1,
    const float* __restrict__ gw2, const float* __restrict__ gb2,
    const float* __restrict__ gw3, const float* __restrict__ gb3,
    unsigned short* __restrict__ geoPc, int pofs)
{
    __shared__ float w[3][GEO*GEO];
    __shared__ float bias[3][GEO];
    int tid = threadIdx.x;
    for (int idx = tid; idx < GEO*GEO; idx += 256) {
        w[0][idx] = gw1[idx]; w[1][idx] = gw2[idx]; w[2][idx] = gw3[idx];
    }
    if (tid < GEO) { bias[0][tid]=gb1[tid]; bias[1][tid]=gb2[tid]; bias[2][tid]=gb3[tid]; }
    __syncthreads();
    int lane = tid & 63;
    int wave = tid >> 6;
    int gwave = blockIdx.x*4 + wave;
    int pair  = pofs + gwave;
    int p = lane >> 4;
    int s = lane & 15;
    int f = s & 7;
    float dm = expf((float)f * (6.907755278982137f/8.0f)); // 1000^(f/8)
    bool is_cos = (s & 8) != 0;
    float scale = 100.f / dm;

    int b  = pair >> 14;
    int ij = pair & 16383;
    int i  = ij >> 7;
    int j  = ij & 127;
    float4 pi = *(const float4*)(prop + (size_t)(b*NP + i)*4);
    float4 pj = *(const float4*)(prop + (size_t)(b*NP + j)*4);
    float wi  = pi.z-pi.x+1.f, hi_ = pi.w-pi.y+1.f;
    float wj  = pj.z-pj.x+1.f, hj  = pj.w-pj.y+1.f;
    float pos;
    if      (p == 0) pos = (0.5f*(pi.x+pi.z) - 0.5f*(pj.x+pj.z)) / wj;
    else if (p == 1) pos = (0.5f*(pi.y+pi.w) - 0.5f*(pj.y+pj.w)) / hj;
    else if (p == 2) pos = wi / wj;
    else             pos = hi_ / hj;
    pos = logf(fmaxf(fabsf(pos), 1e-3f));
    float dv = pos * scale;
    float v = is_cos ? cosf(dv) : sinf(dv);
    #pragma unroll
    for (int layer = 0; layer < 3; ++layer) {
        float acc = bias[layer][lane];
        for (int k = 0; k < GEO; ++k) {
            float vk = __shfl(v, k, 64);
            acc = fmaf(vk, w[layer][k*GEO + lane], acc);
        }
        v = (layer < 2) ? relu_(acc) : acc;
    }
    geoPc[(size_t)gwave*GEO + lane] = f2b(v);
}

// ------------- batched weight transpose+bf16: 8 matrices, N=1024 cols -------------
struct WT8 {
    const float* src[8];
    unsigned short* dst[8];
    int kt[8];     // K/64
    int pre[9];    // prefix of tile counts (kt*16)
};
__global__ __launch_bounds__(256) void k_wTall(WT8 d)
{
    __shared__ float tile[64][65];
    int bid = blockIdx.x;
    int e = 0;
    while (e < 7 && bid >= d.pre[e+1]) ++e;
    int local = bid - d.pre[e];
    int bx = local & 15;      // n-tile (N=1024 -> 16 tiles)
    int by = local >> 4;      // k-tile
    int K = d.kt[e] * 64;
    const float* W = d.src[e];
    unsigned short* WT = d.dst[e];
    int t = threadIdx.x;
    int tc = t & 63, tr = t >> 6;
    #pragma unroll
    for (int r = tr; r < 64; r += 4)
        tile[r][tc] = W[(size_t)(by*64 + r)*1024 + bx*64 + tc];
    __syncthreads();
    #pragma unroll
    for (int r = tr; r < 64; r += 4)
        WT[(size_t)(bx*64 + r)*K + by*64 + tc] = f2b(tile[tc][r]);
}

// ---------------- split-K MFMA GEMM for M=256 layers ----------------
template<bool A_F32>
__global__ __launch_bounds__(256) void k_skmm(
    const void* __restrict__ A1v, const void* __restrict__ A2v,
    int K1, int K2,
    const unsigned short* __restrict__ BT0,
    const unsigned short* __restrict__ BT1,
    float* __restrict__ Cp,
    int KZ, int Kc, int N)
{
    __shared__ unsigned short As[16*32];
    __shared__ unsigned short Bs[128*32];
    int t = threadIdx.x;
    int m0 = blockIdx.x * 16;
    int n0 = blockIdx.y * 128;
    int bz = blockIdx.z;
    int kz = bz % KZ;
    int mat = bz / KZ;
    const unsigned short* BT = mat ? BT1 : BT0;
    int K = K1 + K2;
    int M = gridDim.x * 16;
    int w = t >> 6, l = t & 63;
    int lr = l & 15, lq = l >> 4;
    int arow = t >> 3, ak = (t & 7) * 4;
    int arow2 = t >> 2, ak2 = (t & 3) * 8;
    int brow = t >> 1, bk = (t & 1) * 16;
    f32x4 acc0 = {0.f,0.f,0.f,0.f}, acc1 = {0.f,0.f,0.f,0.f};
    for (int i = 0; i < Kc; i += 32) {
        int kg0 = kz*Kc + i;
        __syncthreads();
        if (A_F32) {
            if (t < 128) {
                int kg = kg0 + ak;
                const float* src = (kg < K1)
                    ? (const float*)A1v + (size_t)(m0+arow)*K1 + kg
                    : (const float*)A2v + (size_t)(m0+arow)*K2 + (kg - K1);
                float4 a4 = *(const float4*)src;
                ushort4 u;
                u.x=f2b(a4.x); u.y=f2b(a4.y); u.z=f2b(a4.z); u.w=f2b(a4.w);
                *(ushort4*)(As + arow*32 + ak) = u;
            }
        } else {
            if (t < 64) {
                const unsigned short* src = (const unsigned short*)A1v + (size_t)(m0+arow2)*K1 + kg0 + ak2;
                *(bf16x8*)(As + arow2*32 + ak2) = *(const bf16x8*)src;
            }
        }
        const unsigned short* srcb = BT + (size_t)(n0+brow)*K + kg0 + bk;
        *(bf16x8*)(Bs + brow*32 + bk)     = *(const bf16x8*)srcb;
        *(bf16x8*)(Bs + brow*32 + bk + 8) = *(const bf16x8*)(srcb + 8);
        __syncthreads();
        bf16x8 af = *(const bf16x8*)(As + lr*32 + lq*8);
        bf16x8 b0 = *(const bf16x8*)(Bs + (w*32      + lr)*32 + lq*8);
        bf16x8 b1 = *(const bf16x8*)(Bs + (w*32 + 16 + lr)*32 + lq*8);
        acc0 = __builtin_amdgcn_mfma_f32_16x16x32_bf16(af, b0, acc0, 0, 0, 0);
        acc1 = __builtin_amdgcn_mfma_f32_16x16x32_bf16(af, b1, acc1, 0, 0, 0);
    }
    float* Co = Cp + (size_t)bz*M*N;
    #pragma unroll
    for (int r = 0; r < 4; ++r) {
        int gr = m0 + lq*4 + r;
        Co[(size_t)gr*N + n0 + w*32      + lr] = acc0[r];
        Co[(size_t)gr*N + n0 + w*32 + 16 + lr] = acc1[r];
    }
}

// ---------------- reduce split-K partials: out = act(sum + bias) ----------------
template<bool RELU, bool OUT_BF16>
__global__ __launch_bounds__(256) void k_red(
    const float* __restrict__ Cp, int KZ,
    const float* __restrict__ bias,
    void* __restrict__ out0, void* __restrict__ out1,
    int MN, int N)
{
    int z = blockIdx.z;
    const float* C = Cp + (size_t)z*KZ*MN;
    void* out = z ? out1 : out0;
    int idx = (blockIdx.x*256 + threadIdx.x) * 4;
    f32x4 s = {0.f,0.f,0.f,0.f};
    for (int k = 0; k < KZ; ++k)
        s += *(const f32x4*)(C + (size_t)k*MN + idx);
    if (bias) s += *(const f32x4*)(bias + (idx & (N-1)));
    if (RELU) { s[0]=relu_(s[0]); s[1]=relu_(s[1]); s[2]=relu_(s[2]); s[3]=relu_(s[3]); }
    if (OUT_BF16) {
        ushort4 u; u.x=f2b(s[0]); u.y=f2b(s[1]); u.z=f2b(s[2]); u.w=f2b(s[3]);
        *(ushort4*)((unsigned short*)out + idx) = u;
    } else {
        float4 o; o.x=s[0]; o.y=s[1]; o.z=s[2]; o.w=s[3];
        *(float4*)((float*)out + idx) = o;
    }
}

// ---------------- bf16 MFMA GEMM (m97 structure): C = act(A@B + bias) ----------
template<bool RELU, bool OUT_BF16>
__global__ __launch_bounds__(256) void k_mgemm(
    const unsigned short* __restrict__ A,
    const unsigned short* __restrict__ BT,
    const float* __restrict__ bias,
    void* __restrict__ Cv, int M, int N, int K)
{
    __shared__ unsigned short As[128*32];
    __shared__ unsigned short Bs[128*32];
    int t  = threadIdx.x;
    int m0 = blockIdx.x * 128;
    int n0 = blockIdx.y * 128;
    int w  = t >> 6, l = t & 63;
    int wm = w & 1, wn = w >> 1;
    int lr = l & 15;
    int lq = l >> 4;

    int s0 = w*2, s1 = w*2 + 1;
    int srow = l >> 2;
    int sko  = (l & 3) * 8;
    int rowA0 = s0*16 + srow, rowA1 = s1*16 + srow;
    unsigned short* ldsA0 = As + s0*512 + l*8;
    unsigned short* ldsA1 = As + s1*512 + l*8;
    unsigned short* ldsB0 = Bs + s0*512 + l*8;
    unsigned short* ldsB1 = Bs + s1*512 + l*8;

    f32x4 acc[4][4];
    #pragma unroll
    for (int mi = 0; mi < 4; ++mi)
        #pragma unroll
        for (int ni = 0; ni < 4; ++ni)
            #pragma unroll
            for (int r = 0; r < 4; ++r) acc[mi][ni][r] = 0.f;

    for (int k0 = 0; k0 < K; k0 += 32) {
        glds16(A  + (size_t)(m0 + rowA0)*K + k0 + sko, ldsA0);
        glds16(A  + (size_t)(m0 + rowA1)*K + k0 + sko, ldsA1);
        glds16(BT + (size_t)(n0 + rowA0)*K + k0 + sko, ldsB0);
        glds16(BT + (size_t)(n0 + rowA1)*K + k0 + sko, ldsB1);
        __syncthreads();
        bf16x8 af[4], bf[4];
        #pragma unroll
        for (int mi = 0; mi < 4; ++mi)
            af[mi] = *(const bf16x8*)(As + (wm*64 + mi*16 + lr)*32 + lq*8);
        #pragma unroll
        for (int ni = 0; ni < 4; ++ni)
            bf[ni] = *(const bf16x8*)(Bs + (wn*64 + ni*16 + lr)*32 + lq*8);
        #pragma unroll
        for (int mi = 0; mi < 4; ++mi)
            #pragma unroll
            for (int ni = 0; ni < 4; ++ni)
                acc[mi][ni] = __builtin_amdgcn_mfma_f32_16x16x32_bf16(af[mi], bf[ni], acc[mi][ni], 0, 0, 0);
        __syncthreads();
    }

    #pragma unroll
    for (int mi = 0; mi < 4; ++mi) {
        #pragma unroll
        for (int ni = 0; ni < 4; ++ni) {
            int gc = n0 + wn*64 + ni*16 + lr;
            int gr = m0 + wm*64 + mi*16 + lq*4;
            float bval = bias ? bias[gc] : 0.f;
            #pragma unroll
            for (int r = 0; r < 4; ++r) {
                float v = acc[mi][ni][r] + bval;
                if (RELU) v = relu_(v);
                if (OUT_BF16) ((unsigned short*)Cv)[(size_t)(gr + r)*N + gc] = f2b(v);
                else          ((float*)Cv)[(size_t)(gr + r)*N + gc] = v;
            }
        }
    }
}

// -------- h1 via MFMA: h1 = relu(geo@W1c + U[b,j] + V[b,i] + b1) -> bf16 ----------
__global__ __launch_bounds__(256) void k_h1m(
    const unsigned short* __restrict__ A,
    const unsigned short* __restrict__ BT,
    const float* __restrict__ b1,
    const float* __restrict__ U, const float* __restrict__ V,
    unsigned short* __restrict__ h1c, int pofs)
{
    __shared__ unsigned short As[128*32];
    __shared__ unsigned short Bs[128*32];
    const int K = GEO;   // 64
    int t  = threadIdx.x;
    int m0 = blockIdx.x * 128;
    int n0 = blockIdx.y * 128;
    int w  = t >> 6, l = t & 63;
    int wm = w & 1, wn = w >> 1;
    int lr = l & 15;
    int lq = l >> 4;

    int s0 = w*2, s1 = w*2 + 1;
    int srow = l >> 2;
    int sko  = (l & 3) * 8;
    int rowA0 = s0*16 + srow, rowA1 = s1*16 + srow;
    unsigned short* ldsA0 = As + s0*512 + l*8;
    unsigned short* ldsA1 = As + s1*512 + l*8;
    unsigned short* ldsB0 = Bs + s0*512 + l*8;
    unsigned short* ldsB1 = Bs + s1*512 + l*8;

    f32x4 acc[4][4];
    #pragma unroll
    for (int mi = 0; mi < 4; ++mi)
        #pragma unroll
        for (int ni = 0; ni < 4; ++ni)
            #pragma unroll
            for (int r = 0; r < 4; ++r) acc[mi][ni][r] = 0.f;

    for (int k0 = 0; k0 < K; k0 += 32) {
        glds16(A  + (size_t)(m0 + rowA0)*K + k0 + sko, ldsA0);
        glds16(A  + (size_t)(m0 + rowA1)*K + k0 + sko, ldsA1);
        glds16(BT + (size_t)(n0 + rowA0)*K + k0 + sko, ldsB0);
        glds16(BT + (size_t)(n0 + rowA1)*K + k0 + sko, ldsB1);
        __syncthreads();
        bf16x8 af[4], bf[4];
        #pragma unroll
        for (int mi = 0; mi < 4; ++mi)
            af[mi] = *(const bf16x8*)(As + (wm*64 + mi*16 + lr)*32 + lq*8);
        #pragma unroll
        for (int ni = 0; ni < 4; ++ni)
            bf[ni] = *(const bf16x8*)(Bs + (wn*64 + ni*16 + lr)*32 + lq*8);
        #pragma unroll
        for (int mi = 0; mi < 4; ++mi)
            #pragma unroll
            for (int ni = 0; ni < 4; ++ni)
                acc[mi][ni] = __builtin_amdgcn_mfma_f32_16x16x32_bf16(af[mi], bf[ni], acc[mi][ni], 0, 0, 0);
        __syncthreads();
    }

    // epilogue: rows of this block are j = 0..127 (p0 multiple of 128), i constant
    int p0 = pofs + m0;
    int bi = p0 >> 7;            // b*NP + i
    int b  = bi >> 7;
    const float* Ubase = U + (size_t)b*NP*D;
    const float* Vrow  = V + (size_t)bi*D;
    #pragma unroll
    for (int ni = 0; ni < 4; ++ni) {
        int gc = n0 + wn*64 + ni*16 + lr;
        float add = Vrow[gc] + b1[gc];
        #pragma unroll
        for (int mi = 0; mi < 4; ++mi) {
            int row = wm*64 + mi*16 + lq*4;
            #pragma unroll
            for (int r = 0; r < 4; ++r) {
                float u = Ubase[(size_t)(row + r)*D + gc];
                float val = acc[mi][ni][r] + u + add;
                h1c[(size_t)(m0 + row + r)*D + gc] = f2b(relu_(val));
            }
        }
    }
}

// ---------------- standalone top-18 over j, sum/8 — fully parallel ----------------
// grid (CH, 16) x 256 threads. Block: row-group bl (128 j) x 64 channels.
// 4 threads/channel, 32 j each (coalesced); two sorted-merge levels in LDS.
#define TK_PAD 19
__global__ __launch_bounds__(256) void k_topk2(
    const unsigned short* __restrict__ fcb,
    float* __restrict__ red_out)
{
    __shared__ float L1[256][TK_PAD];   // 19.5 KB
    __shared__ float L2[128][TK_PAD];   // 9.7 KB
    int t = threadIdx.x;
    int bl = blockIdx.x;
    int cbase = blockIdx.y * 64;
    int cl = t & 63;
    int q = t >> 6;
    const unsigned short* base = fcb + (size_t)(bl*NP + q*32)*D + cbase + cl;
    float sm[TOPKN];
    #pragma unroll
    for (int x = 0; x < TOPKN; ++x) sm[x] = -INFINITY;
    for (int j = 0; j < 32; ++j) {
        float v = b2f(base[(size_t)j*D]);
        #pragma unroll
        for (int x = 0; x < TOPKN; ++x) {
            float mx = fmaxf(sm[x], v);
            v = fminf(sm[x], v);
            sm[x] = mx;
        }
    }
    #pragma unroll
    for (int x = 0; x < TOPKN; ++x) L1[t][x] = sm[x];
    __syncthreads();
    if (t < 128) {
        int h = t >> 6, cc = t & 63;
        const float* la = L1[(2*h)*64 + cc];
        const float* lb = L1[(2*h+1)*64 + cc];
        float* dst = L2[h*64 + cc];
        int ia = 0, ib = 0;
        float av = la[0], bv = lb[0];
        #pragma unroll
        for (int x = 0; x < TOPKN; ++x) {
            bool ta = (av >= bv);
            dst[x] = ta ? av : bv;
            if (ta) { ++ia; av = (ia < TOPKN) ? la[ia] : -INFINITY; }
            else    { ++ib; bv = (ib < TOPKN) ? lb[ib] : -INFINITY; }
        }
    }
    __syncthreads();
    if (t < 64) {
        const float* la = L2[t];
        const float* lb = L2[64 + t];
        int ia = 0, ib = 0;
        float av = la[0], bv = lb[0];
        float s = 0.f;
        #pragma unroll
        for (int x = 0; x < TOPKN; ++x) {
            bool ta = (av >= bv);
            s += ta ? av : bv;
            if (ta) { ++ia; av = (ia < TOPKN) ? la[ia] : -INFINITY; }
            else    { ++ib; bv = (ib < TOPKN) ? lb[ib] : -INFINITY; }
        }
        red_out[(size_t)bl*D + cbase + t] = s * 0.125f;
    }
}

// ---------------- final heads -> sigmoid, f32 out ----------------
__global__ __launch_bounds__(256) void k_final(const float* __restrict__ x,
    const float* __restrict__ subject, const float* __restrict__ obj,
    const float* __restrict__ cs_w, const float* __restrict__ cs_b,
    const float* __restrict__ cso_w, const float* __restrict__ cso_b,
    float* __restrict__ out)
{
    int bi = blockIdx.x;
    int b  = bi >> 7;
    const float* xr = x + (size_t)bi*D;
    const float* sb = subject + (size_t)b*D;
    const float* ob = obj + (size_t)b*D;
    int tid = threadIdx.x;
    float a0 = 0.f, a1 = 0.f;
    for (int k = tid; k < D; k += 256) {
        float xv = xr[k];
        a0 = fmaf(xv, cs_w[k], a0);
        a0 = fmaf(sb[k], cs_w[D+k], a0);
        a1 = fmaf(xv, cso_w[k], a1);
        a1 = fmaf(ob[k], cso_w[D+k], a1);
    }
    __shared__ float r0[256], r1[256];
    r0[tid] = a0; r1[tid] = a1;
    __syncthreads();
    for (int s2 = 128; s2 > 0; s2 >>= 1) {
        if (tid < s2) { r0[tid] += r0[tid+s2]; r1[tid] += r1[tid+s2]; }
        __syncthreads();
    }
    if (tid == 0) {
        out[bi*2+0] = 1.f/(1.f + expf(-(r0[0] + cs_b[0])));
        out[bi*2+1] = 1.f/(1.f + expf(-(r1[0] + cso_b[0])));
    }
}

extern "C" void kernel_launch(void* const* d_in, const int* in_sizes, int n_in,
                              void* d_out, int out_size, void* d_ws, size_t ws_size,
                              hipStream_t stream)
{
    const float* feats   = (const float*)d_in[0];
    const float* subject = (const float*)d_in[1];
    const float* obj     = (const float*)d_in[2];
    const float* prop    = (const float*)d_in[3];
    const float* gp_w1 = (const float*)d_in[4];  const float* gp_b1 = (const float*)d_in[5];
    const float* gp_w2 = (const float*)d_in[6];  const float* gp_b2 = (const float*)d_in[7];
    const float* gp_w3 = (const float*)d_in[8];  const float* gp_b3 = (const float*)d_in[9];
    const float* pm_w1 = (const float*)d_in[10]; const float* pm_b1 = (const float*)d_in[11];
    const float* pm_w2 = (const float*)d_in[12]; const float* pm_b2 = (const float*)d_in[13];
    const float* pm_w3 = (const float*)d_in[14]; const float* pm_b3 = (const float*)d_in[15];
    const float* ag_w1 = (const float*)d_in[16]; const float* ag_b1 = (const float*)d_in[17];
    const float* ag_w2 = (const float*)d_in[18]; const float* ag_b2 = (const float*)d_in[19];
    const float* ag_w3 = (const float*)d_in[20]; const float* ag_b3 = (const float*)d_in[21];
    const float* cs_w  = (const float*)d_in[22]; const float* cs_b  = (const float*)d_in[23];
    const float* cso_w = (const float*)d_in[24]; const float* cso_b = (const float*)d_in[25];
    float* out = (float*)d_out;

    const int M = BS*NP;          // 256
    const int MN = M*D;           // 262144

    // ---- workspace layout (bytes). Persist ~21 MB; Cp aliases the chunk region ----
    char* wsb = (char*)d_ws;
    size_t off = 0;
    auto alloc = [&](size_t bytes) { char* p = wsb + off; off += (bytes + 255) & ~255ull; return p; };
    float* Ub  = (float*)alloc((size_t)MN*4);
    float* Vb  = (float*)alloc((size_t)MN*4);
    float* red = (float*)alloc((size_t)MN*4);
    float* xf  = (float*)alloc((size_t)MN*4);
    unsigned short* xh1b = (unsigned short*)alloc((size_t)MN*2);
    unsigned short* xh2b = (unsigned short*)alloc((size_t)MN*2);
    unsigned short* w1aT = (unsigned short*)alloc((size_t)D*D*2);
    unsigned short* w1bT = (unsigned short*)alloc((size_t)D*D*2);
    unsigned short* w1cT = (unsigned short*)alloc((size_t)D*GEO*2);
    unsigned short* w2T  = (unsigned short*)alloc((size_t)D*D*2);
    unsigned short* w3T  = (unsigned short*)alloc((size_t)D*D*2);
    unsigned short* agw1T= (unsigned short*)alloc((size_t)2*D*D*2);
    unsigned short* agw2T= (unsigned short*)alloc((size_t)D*D*2);
    unsigned short* agw3T= (unsigned short*)alloc((size_t)D*D*2);
    size_t persist = off;

    // shared region: Cp (split-K partials, phases 1&3) ALIASES chunk bufs (phase 2)
    size_t cp_bytes = (size_t)8*MN*4;                              // 8.4 MB
    size_t chunk_unit = (size_t)NP*(GEO*2 + D*2 + D*2 + D*2);      // geo,h1,h2,fcb
    int CH = M;  // try the whole problem in one chunk
    while (CH > 1) {
        size_t region = (size_t)CH*chunk_unit;
        if (region < cp_bytes) region = cp_bytes;
        if (persist + region + 4096 <= ws_size) break;
        CH >>= 1;
    }
    float*          Cp    = (float*)(wsb + persist);
    unsigned short* geoPc = (unsigned short*)(wsb + persist);
    unsigned short* h1c   = geoPc + (size_t)CH*NP*GEO;
    unsigned short* h2c   = h1c   + (size_t)CH*NP*D;
    unsigned short* fcb   = h2c   + (size_t)CH*NP*D;

    // 0) all weight transposes + bf16 in one dispatch (incl. W1c geo slice)
    WT8 d;
    d.src[0]=pm_w1;                d.dst[0]=w1aT;  d.kt[0]=16;
    d.src[1]=pm_w1+(size_t)D*D;    d.dst[1]=w1bT;  d.kt[1]=16;
    d.src[2]=pm_w1+(size_t)2*D*D;  d.dst[2]=w1cT;  d.kt[2]=1;
    d.src[3]=pm_w2;                d.dst[3]=w2T;   d.kt[3]=16;
    d.src[4]=pm_w3;                d.dst[4]=w3T;   d.kt[4]=16;
    d.src[5]=ag_w1;                d.dst[5]=agw1T; d.kt[5]=32;
    d.src[6]=ag_w2;                d.dst[6]=agw2T; d.kt[6]=16;
    d.src[7]=ag_w3;                d.dst[7]=agw3T; d.kt[7]=16;
    d.pre[0]=0;
    for (int e = 0; e < 8; ++e) d.pre[e+1] = d.pre[e] + d.kt[e]*16;
    k_wTall<<<d.pre[8], 256, 0, stream>>>(d);

    // 1) U,V = feats @ {w1a, w1b}: split-K MFMA (KZ=4, 2 mats) + reduce
    k_skmm<true><<<dim3(M/16, D/128, 8), 256, 0, stream>>>(
        feats, nullptr, D, 0, w1aT, w1bT, Cp, 4, 256, D);
    k_red<false,false><<<dim3(MN/1024, 1, 2), 256, 0, stream>>>(
        Cp, 4, nullptr, Ub, Vb, MN, D);

    // 2) chunked over (b,i) rows: geo(bf16) -> h1(MFMA) -> h2 -> fet -> topk
    int nchunks = M/CH;
    for (int cchunk = 0; cchunk < nchunks; ++cchunk) {
        int bi0  = cchunk * CH;
        int pofs = bi0 * NP;
        k_geo<<<CH*NP/4, 256, 0, stream>>>(prop, gp_w1, gp_b1, gp_w2, gp_b2, gp_w3, gp_b3, geoPc, pofs);
        dim3 gBig(CH*NP/128, D/128);
        k_h1m<<<gBig, 256, 0, stream>>>(geoPc, w1cT, pm_b1, Ub, Vb, h1c, pofs);
        k_mgemm<true ,true><<<gBig, 256, 0, stream>>>(h1c, w2T, pm_b2, h2c, CH*NP, D, D);
        k_mgemm<false,true><<<gBig, 256, 0, stream>>>(h2c, w3T, pm_b3, fcb, CH*NP, D, D);
        k_topk2<<<dim3(CH, D/64), 256, 0, stream>>>(fcb, red + (size_t)bi0*D);
    }

    // 3) aggregate MLP via split-K MFMA + fused reduce/activation
    k_skmm<true><<<dim3(M/16, D/128, 8), 256, 0, stream>>>(
        feats, red, D, D, agw1T, nullptr, Cp, 8, 256, D);
    k_red<true,true><<<dim3(MN/1024, 1, 1), 256, 0, stream>>>(
        Cp, 8, ag_b1, xh1b, nullptr, MN, D);
    k_skmm<false><<<dim3(M/16, D/128, 4), 256, 0, stream>>>(
        xh1b, nullptr, D, 0, agw2T, nullptr, Cp, 4, 256, D);
    k_red<true,true><<<dim3(MN/1024, 1, 1), 256, 0, stream>>>(
        Cp, 4, ag_b2, xh2b, nullptr, MN, D);
    k_skmm<false><<<dim3(M/16, D/128, 4), 256, 0, stream>>>(
        xh2b, nullptr, D, 0, agw3T, nullptr, Cp, 4, 256, D);
    k_red<false,false><<<dim3(MN/1024, 1, 1), 256, 0, stream>>>(
        Cp, 4, ag_b3, xf, nullptr, MN, D);

    // 4) sigmoid heads
    k_final<<<M, 256, 0, stream>>>(xf, subject, obj, cs_w, cs_b, cso_w, cso_b, out);
}

// Round 12
// 496.919 us; speedup vs baseline: 1.1636x; 1.1636x over previous
//
#include <hip/hip_runtime.h>
#include <hip/hip_bf16.h>
#include <math.h>

#define D 1024
#define NP 128
#define BS 2
#define GEO 64
#define TOPKN 18
#define NPAIR (BS*NP*NP)   // 32768

__device__ __forceinline__ float relu_(float x){ return fmaxf(x, 0.f); }
__device__ __forceinline__ unsigned short f2b(float x){
    __hip_bfloat16 h = __float2bfloat16(x);
    return *(unsigned short*)&h;
}
__device__ __forceinline__ float b2f(unsigned short u){
    return __uint_as_float((unsigned)u << 16);
}

typedef short bf16x8 __attribute__((ext_vector_type(8)));
typedef float f32x4  __attribute__((ext_vector_type(4)));

// async global->LDS, 16B per lane. LDS dest must be wave-uniform base + lane*16.
__device__ __forceinline__ void glds16(const unsigned short* g, unsigned short* l){
    __builtin_amdgcn_global_load_lds(
        (const __attribute__((address_space(1))) void*)g,
        (__attribute__((address_space(3))) void*)l,
        16, 0, 0);
}

// ------- geo embedding + 3x Linear(64,64) via MFMA (chunk-local, bf16 out) -------
// block: 256 threads = 4 waves; each wave owns 64 consecutive pairs (same b,i).
// emb built per-lane (lane = column) into padded LDS tile; 3 MFMA layers.
#define GSTR 72
__global__ __launch_bounds__(256) void k_geo2(
    const float* __restrict__ prop,
    const float* __restrict__ gw1, const float* __restrict__ gb1,
    const float* __restrict__ gw2, const float* __restrict__ gb2,
    const float* __restrict__ gw3, const float* __restrict__ gb3,
    unsigned short* __restrict__ geoPc, int pofs)
{
    __shared__ unsigned short WT[3][GEO*GSTR];   // W^T bf16, padded: 27.6 KB
    __shared__ float gb[3][GEO];
    __shared__ unsigned short buf[4][GEO*GSTR];  // per-wave act tile: 36.9 KB
    int t = threadIdx.x, l = t & 63, w = t >> 6;

    for (int idx = t; idx < GEO*GEO; idx += 256) {
        int k = idx >> 6, n = idx & 63;          // W[k][n], coalesced over n
        WT[0][n*GSTR + k] = f2b(gw1[idx]);
        WT[1][n*GSTR + k] = f2b(gw2[idx]);
        WT[2][n*GSTR + k] = f2b(gw3[idx]);
    }
    if (t < GEO) { gb[0][t]=gb1[t]; gb[1][t]=gb2[t]; gb[2][t]=gb3[t]; }

    // emb: lane owns column c=l; rows r = 0..63 (pairs pbase..pbase+63, same i)
    int plocal = blockIdx.x*256 + w*64;          // chunk-local pair base
    int pair0  = pofs + plocal;                  // global pair base
    int c = l;
    int p = c >> 4, s = c & 15, f = s & 7;
    float dm = expf((float)f * (6.907755278982137f/8.0f)); // 1000^(f/8)
    bool is_cos = (s & 8) != 0;
    float scale = 100.f / dm;

    int b  = pair0 >> 14;
    int ij = pair0 & 16383;
    int i  = ij >> 7;
    int j0 = ij & 127;
    float4 pi = *(const float4*)(prop + (size_t)(b*NP + i)*4);
    float wi  = pi.z-pi.x+1.f, hi_ = pi.w-pi.y+1.f;
    unsigned short* mybuf = buf[w];
    for (int r = 0; r < 64; ++r) {
        float4 pj = *(const float4*)(prop + (size_t)(b*NP + j0 + r)*4);
        float wj  = pj.z-pj.x+1.f, hj  = pj.w-pj.y+1.f;
        float pos;
        if      (p == 0) pos = (0.5f*(pi.x+pi.z) - 0.5f*(pj.x+pj.z)) / wj;
        else if (p == 1) pos = (0.5f*(pi.y+pi.w) - 0.5f*(pj.y+pj.w)) / hj;
        else if (p == 2) pos = wi / wj;
        else             pos = hi_ / hj;
        pos = logf(fmaxf(fabsf(pos), 1e-3f));
        float dv = pos * scale;
        mybuf[r*GSTR + c] = f2b(is_cos ? cosf(dv) : sinf(dv));
    }
    __syncthreads();

    int lr = l & 15, lq = l >> 4;
    #pragma unroll
    for (int layer = 0; layer < 3; ++layer) {
        const unsigned short* WTl = WT[layer];
        f32x4 acc[4][4];
        #pragma unroll
        for (int mi = 0; mi < 4; ++mi)
            #pragma unroll
            for (int ni = 0; ni < 4; ++ni)
                #pragma unroll
                for (int r = 0; r < 4; ++r) acc[mi][ni][r] = 0.f;
        #pragma unroll
        for (int kc = 0; kc < 2; ++kc) {
            bf16x8 af[4], bf[4];
            #pragma unroll
            for (int mi = 0; mi < 4; ++mi)
                af[mi] = *(const bf16x8*)(mybuf + (mi*16+lr)*GSTR + kc*32 + lq*8);
            #pragma unroll
            for (int ni = 0; ni < 4; ++ni)
                bf[ni] = *(const bf16x8*)(WTl + (ni*16+lr)*GSTR + kc*32 + lq*8);
            #pragma unroll
            for (int mi = 0; mi < 4; ++mi)
                #pragma unroll
                for (int ni = 0; ni < 4; ++ni)
                    acc[mi][ni] = __builtin_amdgcn_mfma_f32_16x16x32_bf16(af[mi], bf[ni], acc[mi][ni], 0, 0, 0);
        }
        __syncthreads();
        #pragma unroll
        for (int mi = 0; mi < 4; ++mi) {
            #pragma unroll
            for (int ni = 0; ni < 4; ++ni) {
                int col = ni*16 + lr;
                float bv = gb[layer][col];
                #pragma unroll
                for (int r = 0; r < 4; ++r) {
                    int row = mi*16 + lq*4 + r;
                    float v = acc[mi][ni][r] + bv;
                    if (layer < 2) {
                        mybuf[row*GSTR + col] = f2b(relu_(v));
                    } else {
                        geoPc[(size_t)(plocal + row)*GEO + col] = f2b(v);
                    }
                }
            }
        }
        __syncthreads();
    }
}

// ------------- batched weight transpose+bf16: 8 matrices, N=1024 cols -------------
struct WT8 {
    const float* src[8];
    unsigned short* dst[8];
    int kt[8];     // K/64
    int pre[9];    // prefix of tile counts (kt*16)
};
__global__ __launch_bounds__(256) void k_wTall(WT8 d)
{
    __shared__ float tile[64][65];
    int bid = blockIdx.x;
    int e = 0;
    while (e < 7 && bid >= d.pre[e+1]) ++e;
    int local = bid - d.pre[e];
    int bx = local & 15;      // n-tile (N=1024 -> 16 tiles)
    int by = local >> 4;      // k-tile
    int K = d.kt[e] * 64;
    const float* W = d.src[e];
    unsigned short* WT = d.dst[e];
    int t = threadIdx.x;
    int tc = t & 63, tr = t >> 6;
    #pragma unroll
    for (int r = tr; r < 64; r += 4)
        tile[r][tc] = W[(size_t)(by*64 + r)*1024 + bx*64 + tc];
    __syncthreads();
    #pragma unroll
    for (int r = tr; r < 64; r += 4)
        WT[(size_t)(bx*64 + r)*K + by*64 + tc] = f2b(tile[tc][r]);
}

// ---------------- split-K MFMA GEMM for M=256 layers ----------------
template<bool A_F32>
__global__ __launch_bounds__(256) void k_skmm(
    const void* __restrict__ A1v, const void* __restrict__ A2v,
    int K1, int K2,
    const unsigned short* __restrict__ BT0,
    const unsigned short* __restrict__ BT1,
    float* __restrict__ Cp,
    int KZ, int Kc, int N)
{
    __shared__ unsigned short As[16*32];
    __shared__ unsigned short Bs[128*32];
    int t = threadIdx.x;
    int m0 = blockIdx.x * 16;
    int n0 = blockIdx.y * 128;
    int bz = blockIdx.z;
    int kz = bz % KZ;
    int mat = bz / KZ;
    const unsigned short* BT = mat ? BT1 : BT0;
    int K = K1 + K2;
    int M = gridDim.x * 16;
    int w = t >> 6, l = t & 63;
    int lr = l & 15, lq = l >> 4;
    int arow = t >> 3, ak = (t & 7) * 4;
    int arow2 = t >> 2, ak2 = (t & 3) * 8;
    int brow = t >> 1, bk = (t & 1) * 16;
    f32x4 acc0 = {0.f,0.f,0.f,0.f}, acc1 = {0.f,0.f,0.f,0.f};
    for (int i = 0; i < Kc; i += 32) {
        int kg0 = kz*Kc + i;
        __syncthreads();
        if (A_F32) {
            if (t < 128) {
                int kg = kg0 + ak;
                const float* src = (kg < K1)
                    ? (const float*)A1v + (size_t)(m0+arow)*K1 + kg
                    : (const float*)A2v + (size_t)(m0+arow)*K2 + (kg - K1);
                float4 a4 = *(const float4*)src;
                ushort4 u;
                u.x=f2b(a4.x); u.y=f2b(a4.y); u.z=f2b(a4.z); u.w=f2b(a4.w);
                *(ushort4*)(As + arow*32 + ak) = u;
            }
        } else {
            if (t < 64) {
                const unsigned short* src = (const unsigned short*)A1v + (size_t)(m0+arow2)*K1 + kg0 + ak2;
                *(bf16x8*)(As + arow2*32 + ak2) = *(const bf16x8*)src;
            }
        }
        const unsigned short* srcb = BT + (size_t)(n0+brow)*K + kg0 + bk;
        *(bf16x8*)(Bs + brow*32 + bk)     = *(const bf16x8*)srcb;
        *(bf16x8*)(Bs + brow*32 + bk + 8) = *(const bf16x8*)(srcb + 8);
        __syncthreads();
        bf16x8 af = *(const bf16x8*)(As + lr*32 + lq*8);
        bf16x8 b0 = *(const bf16x8*)(Bs + (w*32      + lr)*32 + lq*8);
        bf16x8 b1 = *(const bf16x8*)(Bs + (w*32 + 16 + lr)*32 + lq*8);
        acc0 = __builtin_amdgcn_mfma_f32_16x16x32_bf16(af, b0, acc0, 0, 0, 0);
        acc1 = __builtin_amdgcn_mfma_f32_16x16x32_bf16(af, b1, acc1, 0, 0, 0);
    }
    float* Co = Cp + (size_t)bz*M*N;
    #pragma unroll
    for (int r = 0; r < 4; ++r) {
        int gr = m0 + lq*4 + r;
        Co[(size_t)gr*N + n0 + w*32      + lr] = acc0[r];
        Co[(size_t)gr*N + n0 + w*32 + 16 + lr] = acc1[r];
    }
}

// ---------------- reduce split-K partials: out = act(sum + bias) ----------------
template<bool RELU, bool OUT_BF16>
__global__ __launch_bounds__(256) void k_red(
    const float* __restrict__ Cp, int KZ,
    const float* __restrict__ bias,
    void* __restrict__ out0, void* __restrict__ out1,
    int MN, int N)
{
    int z = blockIdx.z;
    const float* C = Cp + (size_t)z*KZ*MN;
    void* out = z ? out1 : out0;
    int idx = (blockIdx.x*256 + threadIdx.x) * 4;
    f32x4 s = {0.f,0.f,0.f,0.f};
    for (int k = 0; k < KZ; ++k)
        s += *(const f32x4*)(C + (size_t)k*MN + idx);
    if (bias) s += *(const f32x4*)(bias + (idx & (N-1)));
    if (RELU) { s[0]=relu_(s[0]); s[1]=relu_(s[1]); s[2]=relu_(s[2]); s[3]=relu_(s[3]); }
    if (OUT_BF16) {
        ushort4 u; u.x=f2b(s[0]); u.y=f2b(s[1]); u.z=f2b(s[2]); u.w=f2b(s[3]);
        *(ushort4*)((unsigned short*)out + idx) = u;
    } else {
        float4 o; o.x=s[0]; o.y=s[1]; o.z=s[2]; o.w=s[3];
        *(float4*)((float*)out + idx) = o;
    }
}

// ------- bf16 MFMA GEMM (m97 structure, BK=64 two-panel): C = act(A@B + bias) -----
template<bool RELU, bool OUT_BF16>
__global__ __launch_bounds__(256) void k_mgemm(
    const unsigned short* __restrict__ A,
    const unsigned short* __restrict__ BT,
    const float* __restrict__ bias,
    void* __restrict__ Cv, int M, int N, int K)
{
    __shared__ unsigned short As[2*128*32];   // 16 KB
    __shared__ unsigned short Bs[2*128*32];   // 16 KB
    int t  = threadIdx.x;
    int m0 = blockIdx.x * 128;
    int n0 = blockIdx.y * 128;
    int w  = t >> 6, l = t & 63;
    int wm = w & 1, wn = w >> 1;
    int lr = l & 15;
    int lq = l >> 4;

    int s0 = w*2, s1 = w*2 + 1;
    int srow = l >> 2;
    int sko  = (l & 3) * 8;
    int rowA0 = s0*16 + srow, rowA1 = s1*16 + srow;

    f32x4 acc[4][4];
    #pragma unroll
    for (int mi = 0; mi < 4; ++mi)
        #pragma unroll
        for (int ni = 0; ni < 4; ++ni)
            #pragma unroll
            for (int r = 0; r < 4; ++r) acc[mi][ni][r] = 0.f;

    for (int k0 = 0; k0 < K; k0 += 64) {
        #pragma unroll
        for (int q = 0; q < 2; ++q) {
            int kg = k0 + q*32 + sko;
            glds16(A  + (size_t)(m0 + rowA0)*K + kg, As + q*4096 + s0*512 + l*8);
            glds16(A  + (size_t)(m0 + rowA1)*K + kg, As + q*4096 + s1*512 + l*8);
            glds16(BT + (size_t)(n0 + rowA0)*K + kg, Bs + q*4096 + s0*512 + l*8);
            glds16(BT + (size_t)(n0 + rowA1)*K + kg, Bs + q*4096 + s1*512 + l*8);
        }
        __syncthreads();
        #pragma unroll
        for (int q = 0; q < 2; ++q) {
            bf16x8 af[4], bf[4];
            #pragma unroll
            for (int mi = 0; mi < 4; ++mi)
                af[mi] = *(const bf16x8*)(As + q*4096 + (wm*64 + mi*16 + lr)*32 + lq*8);
            #pragma unroll
            for (int ni = 0; ni < 4; ++ni)
                bf[ni] = *(const bf16x8*)(Bs + q*4096 + (wn*64 + ni*16 + lr)*32 + lq*8);
            #pragma unroll
            for (int mi = 0; mi < 4; ++mi)
                #pragma unroll
                for (int ni = 0; ni < 4; ++ni)
                    acc[mi][ni] = __builtin_amdgcn_mfma_f32_16x16x32_bf16(af[mi], bf[ni], acc[mi][ni], 0, 0, 0);
        }
        __syncthreads();
    }

    #pragma unroll
    for (int mi = 0; mi < 4; ++mi) {
        #pragma unroll
        for (int ni = 0; ni < 4; ++ni) {
            int gc = n0 + wn*64 + ni*16 + lr;
            int gr = m0 + wm*64 + mi*16 + lq*4;
            float bval = bias ? bias[gc] : 0.f;
            #pragma unroll
            for (int r = 0; r < 4; ++r) {
                float v = acc[mi][ni][r] + bval;
                if (RELU) v = relu_(v);
                if (OUT_BF16) ((unsigned short*)Cv)[(size_t)(gr + r)*N + gc] = f2b(v);
                else          ((float*)Cv)[(size_t)(gr + r)*N + gc] = v;
            }
        }
    }
}

// -------- h1 via MFMA (K=64, single iteration): relu(geo@W1c + U + V + b1) --------
__global__ __launch_bounds__(256) void k_h1m(
    const unsigned short* __restrict__ A,
    const unsigned short* __restrict__ BT,
    const float* __restrict__ b1,
    const unsigned short* __restrict__ U, const unsigned short* __restrict__ V,
    unsigned short* __restrict__ h1c, int pofs)
{
    __shared__ unsigned short As[2*128*32];
    __shared__ unsigned short Bs[2*128*32];
    const int K = GEO;   // 64
    int t  = threadIdx.x;
    int m0 = blockIdx.x * 128;
    int n0 = blockIdx.y * 128;
    int w  = t >> 6, l = t & 63;
    int wm = w & 1, wn = w >> 1;
    int lr = l & 15;
    int lq = l >> 4;

    int s0 = w*2, s1 = w*2 + 1;
    int srow = l >> 2;
    int sko  = (l & 3) * 8;
    int rowA0 = s0*16 + srow, rowA1 = s1*16 + srow;

    f32x4 acc[4][4];
    #pragma unroll
    for (int mi = 0; mi < 4; ++mi)
        #pragma unroll
        for (int ni = 0; ni < 4; ++ni)
            #pragma unroll
            for (int r = 0; r < 4; ++r) acc[mi][ni][r] = 0.f;

    #pragma unroll
    for (int q = 0; q < 2; ++q) {
        int kg = q*32 + sko;
        glds16(A  + (size_t)(m0 + rowA0)*K + kg, As + q*4096 + s0*512 + l*8);
        glds16(A  + (size_t)(m0 + rowA1)*K + kg, As + q*4096 + s1*512 + l*8);
        glds16(BT + (size_t)(n0 + rowA0)*K + kg, Bs + q*4096 + s0*512 + l*8);
        glds16(BT + (size_t)(n0 + rowA1)*K + kg, Bs + q*4096 + s1*512 + l*8);
    }
    __syncthreads();
    #pragma unroll
    for (int q = 0; q < 2; ++q) {
        bf16x8 af[4], bf[4];
        #pragma unroll
        for (int mi = 0; mi < 4; ++mi)
            af[mi] = *(const bf16x8*)(As + q*4096 + (wm*64 + mi*16 + lr)*32 + lq*8);
        #pragma unroll
        for (int ni = 0; ni < 4; ++ni)
            bf[ni] = *(const bf16x8*)(Bs + q*4096 + (wn*64 + ni*16 + lr)*32 + lq*8);
        #pragma unroll
        for (int mi = 0; mi < 4; ++mi)
            #pragma unroll
            for (int ni = 0; ni < 4; ++ni)
                acc[mi][ni] = __builtin_amdgcn_mfma_f32_16x16x32_bf16(af[mi], bf[ni], acc[mi][ni], 0, 0, 0);
    }

    // epilogue: rows of this block are j = 0..127 (p0 multiple of 128), i constant
    int p0 = pofs + m0;
    int bi = p0 >> 7;            // b*NP + i
    int b  = bi >> 7;
    const unsigned short* Ubase = U + (size_t)b*NP*D;
    const unsigned short* Vrow  = V + (size_t)bi*D;
    #pragma unroll
    for (int ni = 0; ni < 4; ++ni) {
        int gc = n0 + wn*64 + ni*16 + lr;
        float add = b2f(Vrow[gc]) + b1[gc];
        #pragma unroll
        for (int mi = 0; mi < 4; ++mi) {
            int row = wm*64 + mi*16 + lq*4;
            #pragma unroll
            for (int r = 0; r < 4; ++r) {
                float u = b2f(Ubase[(size_t)(row + r)*D + gc]);
                float val = acc[mi][ni][r] + u + add;
                h1c[(size_t)(m0 + row + r)*D + gc] = f2b(relu_(val));
            }
        }
    }
}

// ---------------- standalone top-18 over j, sum/8 — fully parallel ----------------
#define TK_PAD 19
__global__ __launch_bounds__(256) void k_topk2(
    const unsigned short* __restrict__ fcb,
    float* __restrict__ red_out)
{
    __shared__ float L1[256][TK_PAD];
    __shared__ float L2[128][TK_PAD];
    int t = threadIdx.x;
    int bl = blockIdx.x;
    int cbase = blockIdx.y * 64;
    int cl = t & 63;
    int q = t >> 6;
    const unsigned short* base = fcb + (size_t)(bl*NP + q*32)*D + cbase + cl;
    float sm[TOPKN];
    #pragma unroll
    for (int x = 0; x < TOPKN; ++x) sm[x] = -INFINITY;
    for (int j = 0; j < 32; ++j) {
        float v = b2f(base[(size_t)j*D]);
        #pragma unroll
        for (int x = 0; x < TOPKN; ++x) {
            float mx = fmaxf(sm[x], v);
            v = fminf(sm[x], v);
            sm[x] = mx;
        }
    }
    #pragma unroll
    for (int x = 0; x < TOPKN; ++x) L1[t][x] = sm[x];
    __syncthreads();
    if (t < 128) {
        int h = t >> 6, cc = t & 63;
        const float* la = L1[(2*h)*64 + cc];
        const float* lb = L1[(2*h+1)*64 + cc];
        float* dst = L2[h*64 + cc];
        int ia = 0, ib = 0;
        float av = la[0], bv = lb[0];
        #pragma unroll
        for (int x = 0; x < TOPKN; ++x) {
            bool ta = (av >= bv);
            dst[x] = ta ? av : bv;
            if (ta) { ++ia; av = (ia < TOPKN) ? la[ia] : -INFINITY; }
            else    { ++ib; bv = (ib < TOPKN) ? lb[ib] : -INFINITY; }
        }
    }
    __syncthreads();
    if (t < 64) {
        const float* la = L2[t];
        const float* lb = L2[64 + t];
        int ia = 0, ib = 0;
        float av = la[0], bv = lb[0];
        float s = 0.f;
        #pragma unroll
        for (int x = 0; x < TOPKN; ++x) {
            bool ta = (av >= bv);
            s += ta ? av : bv;
            if (ta) { ++ia; av = (ia < TOPKN) ? la[ia] : -INFINITY; }
            else    { ++ib; bv = (ib < TOPKN) ? lb[ib] : -INFINITY; }
        }
        red_out[(size_t)bl*D + cbase + t] = s * 0.125f;
    }
}

// ---------------- final heads -> sigmoid, f32 out ----------------
__global__ __launch_bounds__(256) void k_final(const float* __restrict__ x,
    const float* __restrict__ subject, const float* __restrict__ obj,
    const float* __restrict__ cs_w, const float* __restrict__ cs_b,
    const float* __restrict__ cso_w, const float* __restrict__ cso_b,
    float* __restrict__ out)
{
    int bi = blockIdx.x;
    int b  = bi >> 7;
    const float* xr = x + (size_t)bi*D;
    const float* sb = subject + (size_t)b*D;
    const float* ob = obj + (size_t)b*D;
    int tid = threadIdx.x;
    float a0 = 0.f, a1 = 0.f;
    for (int k = tid; k < D; k += 256) {
        float xv = xr[k];
        a0 = fmaf(xv, cs_w[k], a0);
        a0 = fmaf(sb[k], cs_w[D+k], a0);
        a1 = fmaf(xv, cso_w[k], a1);
        a1 = fmaf(ob[k], cso_w[D+k], a1);
    }
    __shared__ float r0[256], r1[256];
    r0[tid] = a0; r1[tid] = a1;
    __syncthreads();
    for (int s2 = 128; s2 > 0; s2 >>= 1) {
        if (tid < s2) { r0[tid] += r0[tid+s2]; r1[tid] += r1[tid+s2]; }
        __syncthreads();
    }
    if (tid == 0) {
        out[bi*2+0] = 1.f/(1.f + expf(-(r0[0] + cs_b[0])));
        out[bi*2+1] = 1.f/(1.f + expf(-(r1[0] + cso_b[0])));
    }
}

extern "C" void kernel_launch(void* const* d_in, const int* in_sizes, int n_in,
                              void* d_out, int out_size, void* d_ws, size_t ws_size,
                              hipStream_t stream)
{
    const float* feats   = (const float*)d_in[0];
    const float* subject = (const float*)d_in[1];
    const float* obj     = (const float*)d_in[2];
    const float* prop    = (const float*)d_in[3];
    const float* gp_w1 = (const float*)d_in[4];  const float* gp_b1 = (const float*)d_in[5];
    const float* gp_w2 = (const float*)d_in[6];  const float* gp_b2 = (const float*)d_in[7];
    const float* gp_w3 = (const float*)d_in[8];  const float* gp_b3 = (const float*)d_in[9];
    const float* pm_w1 = (const float*)d_in[10]; const float* pm_b1 = (const float*)d_in[11];
    const float* pm_w2 = (const float*)d_in[12]; const float* pm_b2 = (const float*)d_in[13];
    const float* pm_w3 = (const float*)d_in[14]; const float* pm_b3 = (const float*)d_in[15];
    const float* ag_w1 = (const float*)d_in[16]; const float* ag_b1 = (const float*)d_in[17];
    const float* ag_w2 = (const float*)d_in[18]; const float* ag_b2 = (const float*)d_in[19];
    const float* ag_w3 = (const float*)d_in[20]; const float* ag_b3 = (const float*)d_in[21];
    const float* cs_w  = (const float*)d_in[22]; const float* cs_b  = (const float*)d_in[23];
    const float* cso_w = (const float*)d_in[24]; const float* cso_b = (const float*)d_in[25];
    float* out = (float*)d_out;

    const int M = BS*NP;          // 256
    const int MN = M*D;           // 262144

    // ---- workspace layout (bytes). Cp aliases the chunk region ----
    char* wsb = (char*)d_ws;
    size_t off = 0;
    auto alloc = [&](size_t bytes) { char* p = wsb + off; off += (bytes + 255) & ~255ull; return p; };
    unsigned short* Ub = (unsigned short*)alloc((size_t)MN*2);
    unsigned short* Vb = (unsigned short*)alloc((size_t)MN*2);
    float* red = (float*)alloc((size_t)MN*4);
    float* xf  = (float*)alloc((size_t)MN*4);
    unsigned short* xh1b = (unsigned short*)alloc((size_t)MN*2);
    unsigned short* xh2b = (unsigned short*)alloc((size_t)MN*2);
    unsigned short* w1aT = (unsigned short*)alloc((size_t)D*D*2);
    unsigned short* w1bT = (unsigned short*)alloc((size_t)D*D*2);
    unsigned short* w1cT = (unsigned short*)alloc((size_t)D*GEO*2);
    unsigned short* w2T  = (unsigned short*)alloc((size_t)D*D*2);
    unsigned short* w3T  = (unsigned short*)alloc((size_t)D*D*2);
    unsigned short* agw1T= (unsigned short*)alloc((size_t)2*D*D*2);
    unsigned short* agw2T= (unsigned short*)alloc((size_t)D*D*2);
    unsigned short* agw3T= (unsigned short*)alloc((size_t)D*D*2);
    size_t persist = off;

    // shared region: Cp (split-K partials, phases 1&3) ALIASES chunk bufs (phase 2)
    size_t cp_bytes = (size_t)8*MN*4;                              // 8.4 MB
    size_t chunk_unit = (size_t)NP*(GEO*2 + D*2 + D*2 + D*2);      // geo,h1,h2,fcb
    int CH = M;  // try the whole problem in one chunk
    while (CH > 2) {
        size_t region = (size_t)CH*chunk_unit;
        if (region < cp_bytes) region = cp_bytes;
        if (persist + region + 4096 <= ws_size) break;
        CH >>= 1;
    }
    float*          Cp    = (float*)(wsb + persist);
    unsigned short* geoPc = (unsigned short*)(wsb + persist);
    unsigned short* h1c   = geoPc + (size_t)CH*NP*GEO;
    unsigned short* h2c   = h1c   + (size_t)CH*NP*D;
    unsigned short* fcb   = h2c   + (size_t)CH*NP*D;

    // 0) all weight transposes + bf16 in one dispatch (incl. W1c geo slice)
    WT8 d;
    d.src[0]=pm_w1;                d.dst[0]=w1aT;  d.kt[0]=16;
    d.src[1]=pm_w1+(size_t)D*D;    d.dst[1]=w1bT;  d.kt[1]=16;
    d.src[2]=pm_w1+(size_t)2*D*D;  d.dst[2]=w1cT;  d.kt[2]=1;
    d.src[3]=pm_w2;                d.dst[3]=w2T;   d.kt[3]=16;
    d.src[4]=pm_w3;                d.dst[4]=w3T;   d.kt[4]=16;
    d.src[5]=ag_w1;                d.dst[5]=agw1T; d.kt[5]=32;
    d.src[6]=ag_w2;                d.dst[6]=agw2T; d.kt[6]=16;
    d.src[7]=ag_w3;                d.dst[7]=agw3T; d.kt[7]=16;
    d.pre[0]=0;
    for (int e = 0; e < 8; ++e) d.pre[e+1] = d.pre[e] + d.kt[e]*16;
    k_wTall<<<d.pre[8], 256, 0, stream>>>(d);

    // 1) U,V = feats @ {w1a, w1b}: split-K MFMA (KZ=4, 2 mats) + reduce (bf16 out)
    k_skmm<true><<<dim3(M/16, D/128, 8), 256, 0, stream>>>(
        feats, nullptr, D, 0, w1aT, w1bT, Cp, 4, 256, D);
    k_red<false,true><<<dim3(MN/1024, 1, 2), 256, 0, stream>>>(
        Cp, 4, nullptr, Ub, Vb, MN, D);

    // 2) chunked over (b,i) rows: geo(MFMA) -> h1(MFMA) -> h2 -> fet -> topk
    int nchunks = M/CH;
    for (int cchunk = 0; cchunk < nchunks; ++cchunk) {
        int bi0  = cchunk * CH;
        int pofs = bi0 * NP;
        k_geo2<<<CH*NP/256, 256, 0, stream>>>(prop, gp_w1, gp_b1, gp_w2, gp_b2, gp_w3, gp_b3, geoPc, pofs);
        dim3 gBig(CH*NP/128, D/128);
        k_h1m<<<gBig, 256, 0, stream>>>(geoPc, w1cT, pm_b1, Ub, Vb, h1c, pofs);
        k_mgemm<true ,true><<<gBig, 256, 0, stream>>>(h1c, w2T, pm_b2, h2c, CH*NP, D, D);
        k_mgemm<false,true><<<gBig, 256, 0, stream>>>(h2c, w3T, pm_b3, fcb, CH*NP, D, D);
        k_topk2<<<dim3(CH, D/64), 256, 0, stream>>>(fcb, red + (size_t)bi0*D);
    }

    // 3) aggregate MLP via split-K MFMA + fused reduce/activation
    k_skmm<true><<<dim3(M/16, D/128, 8), 256, 0, stream>>>(
        feats, red, D, D, agw1T, nullptr, Cp, 8, 256, D);
    k_red<true,true><<<dim3(MN/1024, 1, 1), 256, 0, stream>>>(
        Cp, 8, ag_b1, xh1b, nullptr, MN, D);
    k_skmm<false><<<dim3(M/16, D/128, 4), 256, 0, stream>>>(
        xh1b, nullptr, D, 0, agw2T, nullptr, Cp, 4, 256, D);
    k_red<true,true><<<dim3(MN/1024, 1, 1), 256, 0, stream>>>(
        Cp, 4, ag_b2, xh2b, nullptr, MN, D);
    k_skmm<false><<<dim3(M/16, D/128, 4), 256, 0, stream>>>(
        xh2b, nullptr, D, 0, agw3T, nullptr, Cp, 4, 256, D);
    k_red<false,false><<<dim3(MN/1024, 1, 1), 256, 0, stream>>>(
        Cp, 4, ag_b3, xf, nullptr, MN, D);

    // 4) sigmoid heads
    k_final<<<M, 256, 0, stream>>>(xf, subject, obj, cs_w, cs_b, cso_w, cso_b, out);
}